// Round 11
// baseline (407.785 us; speedup 1.0000x reference)
//
#include <hip/hip_runtime.h>
#include <hip/hip_bf16.h>

#define DEV_INLINE __device__ __forceinline__

static constexpr int WAVE = 64;
static constexpr float FP8_SCALE = 64.0f;
static constexpr float FP8_INV   = 1.0f / 64.0f;

typedef float floatx2 __attribute__((ext_vector_type(2)));

DEV_INLINE float wave_sum(float v) {
    #pragma unroll
    for (int o = 32; o > 0; o >>= 1) v += __shfl_xor(v, o);
    return v;
}
DEV_INLINE float leaky02(float x) { return x > 0.f ? x : 0.2f * x; }
DEV_INLINE unsigned short f2b(float f) {
    __hip_bfloat16 b = __float2bfloat16(f);
    return *reinterpret_cast<unsigned short*>(&b);
}
DEV_INLINE float b2f(unsigned short u) {
    unsigned int x = ((unsigned int)u) << 16;
    return __uint_as_float(x);
}

// ---------------- CSR build ----------------
__global__ void count_kernel(const int* __restrict__ ei, int E, int* __restrict__ deg) {
    int i = blockIdx.x * blockDim.x + threadIdx.x;
    if (i >= E) return;
    atomicAdd(&deg[ei[E + i]], 1);
}

__global__ __launch_bounds__(256)
void scan_partial_kernel(const int* __restrict__ deg, int* __restrict__ blocksum, int n) {
    int t = threadIdx.x;
    int base = blockIdx.x * 1024 + t * 4;
    int s = 0;
    #pragma unroll
    for (int j = 0; j < 4; ++j) { int i = base + j; if (i < n) s += deg[i]; }
    __shared__ int red[4];
    s = (int)wave_sum((float)s);
    if ((t & 63) == 0) red[t >> 6] = s;
    __syncthreads();
    if (t == 0) blocksum[blockIdx.x] = red[0] + red[1] + red[2] + red[3];
}

__global__ __launch_bounds__(64)
void scan_blocksum_kernel(int* __restrict__ blocksum, int* __restrict__ off, int nblk, int n) {
    int lane = threadIdx.x;
    int v = (lane < nblk) ? blocksum[lane] : 0;
    int orig = v;
    #pragma unroll
    for (int o = 1; o < 64; o <<= 1) {
        int u = __shfl_up(v, o);
        if (lane >= o) v += u;
    }
    if (lane < nblk) blocksum[lane] = v - orig;
    if (lane == 63) off[n] = v;
}

__global__ __launch_bounds__(256)
void scan_final_kernel(const int* __restrict__ deg, const int* __restrict__ blockoff,
                       int* __restrict__ off, int* __restrict__ cursor, int n) {
    int t = threadIdx.x, lane = t & 63, wid = t >> 6;
    int base = blockIdx.x * 1024 + t * 4;
    int v[4], s = 0;
    #pragma unroll
    for (int j = 0; j < 4; ++j) {
        int i = base + j;
        v[j] = (i < n) ? deg[i] : 0;
        s += v[j];
    }
    int incl = s;
    #pragma unroll
    for (int o = 1; o < 64; o <<= 1) {
        int u = __shfl_up(incl, o);
        if (lane >= o) incl += u;
    }
    __shared__ int wtot[4];
    if (lane == 63) wtot[wid] = incl;
    __syncthreads();
    int woff = 0;
    for (int w0 = 0; w0 < wid; ++w0) woff += wtot[w0];
    int run = blockoff[blockIdx.x] + woff + incl - s;
    #pragma unroll
    for (int j = 0; j < 4; ++j) {
        int i = base + j;
        if (i < n) { off[i] = run; cursor[i] = run; }
        run += v[j];
    }
}

// fill: CSR src + edge attributes (bf16x8, 16B scatter) in CSR order
__global__ void fill_kernel(const int* __restrict__ ei, const float* __restrict__ ea, int E,
                            int* __restrict__ cursor, int* __restrict__ esrc,
                            unsigned short* __restrict__ ea16) {
    int i = blockIdx.x * blockDim.x + threadIdx.x;
    if (i >= E) return;
    int d = ei[E + i];
    int pos = atomicAdd(&cursor[d], 1);
    esrc[pos] = ei[i];
    const float4* p = reinterpret_cast<const float4*>(ea + (size_t)i * 8);
    float4 a0 = p[0], a1 = p[1];
    ushort4 u0, u1;
    u0.x = f2b(a0.x); u0.y = f2b(a0.y); u0.z = f2b(a0.z); u0.w = f2b(a0.w);
    u1.x = f2b(a1.x); u1.y = f2b(a1.y); u1.z = f2b(a1.z); u1.w = f2b(a1.w);
    ushort4* q = reinterpret_cast<ushort4*>(ea16 + (size_t)pos * 8);
    q[0] = u0; q[1] = u1;
}

// ---------------- both layers' watt in one launch ----------------
__global__ void watt2_kernel(const float* __restrict__ We0, const float* __restrict__ att0,
                             const float* __restrict__ be0,
                             const float* __restrict__ We1, const float* __restrict__ att1,
                             const float* __restrict__ be1,
                             float* __restrict__ watt) {
    int L = blockIdx.x;
    const float* We  = L ? We1 : We0;
    const float* att = L ? att1 : att0;
    const float* be  = L ? be1 : be0;
    int H = L ? 128 : 64;
    int lane = threadIdx.x;
    for (int k = 0; k < 8; ++k) {
        float s = 0.f;
        for (int h = lane; h < H; h += WAVE) s += We[k * H + h] * att[h];
        s = wave_sum(s);
        if (lane == 0) watt[L * 16 + k] = s;
    }
    float s = 0.f;
    for (int h = lane; h < H; h += WAVE) s += be[h] * att[h];
    s = wave_sum(s);
    if (lane == 0) watt[L * 16 + 8] = s;
}

// ---------------- per-layer streaming scores in CSR order ----------------
__global__ void score_csr_kernel(const int* __restrict__ esrc, const unsigned short* __restrict__ ea16,
                                 const float* __restrict__ watt, const float* __restrict__ nscore,
                                 float* __restrict__ sc_csr, int E) {
    int pos = blockIdx.x * blockDim.x + threadIdx.x;
    if (pos >= E) return;
    const ushort4* p = reinterpret_cast<const ushort4*>(ea16 + (size_t)pos * 8);
    ushort4 u0 = p[0], u1 = p[1];
    float s = watt[8];
    s += b2f(u0.x) * watt[0] + b2f(u0.y) * watt[1] + b2f(u0.z) * watt[2] + b2f(u0.w) * watt[3];
    s += b2f(u1.x) * watt[4] + b2f(u1.y) * watt[5] + b2f(u1.z) * watt[6] + b2f(u1.w) * watt[7];
    sc_csr[pos] = leaky02(nscore[esrc[pos]] + s);
}

// ---------------- node linear (LDS-tiled register-blocked GEMM) ----------------
template <int H, int NB, bool INBF16>
__global__ __launch_bounds__(256)
void nodelin_kernel(const float* __restrict__ hf, const unsigned short* __restrict__ hb,
                    const int* __restrict__ xidx,
                    const float* __restrict__ Wm, const float* __restrict__ bm,
                    const float* __restrict__ Ws, const float* __restrict__ bs,
                    const float* __restrict__ att,
                    unsigned char* __restrict__ hWm8, unsigned short* __restrict__ hWsb,
                    float* __restrict__ nscore, int n) {
    constexpr int F4  = H / 4;
    constexpr int NC  = 256 / F4;
    constexpr int NPT = NB / NC;
    constexpr int LDW = 68;
    __shared__ float sh[NB][LDW];
    int n0 = blockIdx.x * NB;
    int tid = threadIdx.x;

    for (int i = tid; i < NB * 16; i += 256) {
        int node = i >> 4, q = i & 15;
        int row = n0 + node;
        float4 v = make_float4(0.f, 0.f, 0.f, 0.f);
        if (row < n) {
            if constexpr (INBF16) {
                ushort4 u = reinterpret_cast<const ushort4*>(hb + (size_t)row * 64)[q];
                v = make_float4(b2f(u.x), b2f(u.y), b2f(u.z), b2f(u.w));
            } else {
                int src = xidx ? xidx[row] : row;
                v = reinterpret_cast<const float4*>(hf + (size_t)src * 64)[q];
            }
        }
        reinterpret_cast<float4*>(&sh[node][0])[q] = v;
    }
    __syncthreads();

    int f4 = (tid % F4) * 4;
    int j0 = tid / F4;
    float4 am[NPT], as[NPT];
    float4 bm4 = *reinterpret_cast<const float4*>(bm + f4);
    float4 bs4 = *reinterpret_cast<const float4*>(bs + f4);
    #pragma unroll
    for (int p = 0; p < NPT; ++p) { am[p] = bm4; as[p] = bs4; }

    for (int k4 = 0; k4 < 16; ++k4) {
        float4 hv[NPT];
        #pragma unroll
        for (int p = 0; p < NPT; ++p)
            hv[p] = reinterpret_cast<const float4*>(&sh[j0 + p * NC][0])[k4];
        #pragma unroll
        for (int kk = 0; kk < 4; ++kk) {
            int k = k4 * 4 + kk;
            float4 wm = *reinterpret_cast<const float4*>(Wm + k * H + f4);
            float4 ws = *reinterpret_cast<const float4*>(Ws + k * H + f4);
            #pragma unroll
            for (int p = 0; p < NPT; ++p) {
                float hk = (&hv[p].x)[kk];
                am[p].x += hk * wm.x; am[p].y += hk * wm.y;
                am[p].z += hk * wm.z; am[p].w += hk * wm.w;
                as[p].x += hk * ws.x; as[p].y += hk * ws.y;
                as[p].z += hk * ws.z; as[p].w += hk * ws.w;
            }
        }
    }

    float4 at4 = *reinterpret_cast<const float4*>(att + f4);
    #pragma unroll
    for (int p = 0; p < NPT; ++p) {
        int row = n0 + j0 + p * NC;
        float sc = am[p].x * at4.x + am[p].y * at4.y + am[p].z * at4.z + am[p].w * at4.w;
        #pragma unroll
        for (int o = 1; o < F4; o <<= 1) sc += __shfl_xor(sc, o);
        if (row < n) {
            int pk = 0;
            pk = __builtin_amdgcn_cvt_pk_fp8_f32(am[p].x * FP8_SCALE, am[p].y * FP8_SCALE, pk, false);
            pk = __builtin_amdgcn_cvt_pk_fp8_f32(am[p].z * FP8_SCALE, am[p].w * FP8_SCALE, pk, true);
            *reinterpret_cast<unsigned int*>(hWm8 + (size_t)row * H + f4) = (unsigned int)pk;
            ushort4 sb;
            sb.x = f2b(as[p].x); sb.y = f2b(as[p].y); sb.z = f2b(as[p].z); sb.w = f2b(as[p].w);
            *reinterpret_cast<ushort4*>(hWsb + (size_t)row * H + f4) = sb;
            if ((tid % F4) == 0) nscore[row] = sc;
        }
    }
}

// ---------------- aggregation: LSUB-lane subgroup per node ----------------
// cea channels repeat every 8 lanes (dup = LSUB/8 duplicates); each duplicate
// covers the j ≡ jsel (mod dup) slice so the xor-merge combines DISJOINT partials.
template <int H>
__global__ __launch_bounds__(64)
void agg_kernel(const int* __restrict__ csr_off,
                const int* __restrict__ esrc, const float* __restrict__ sc_csr,
                const unsigned short* __restrict__ ea16,
                const float* __restrict__ We, const float* __restrict__ be,
                const unsigned char* __restrict__ hWm8, const unsigned short* __restrict__ hWsb,
                unsigned short* __restrict__ hout, int n) {
    constexpr int LSUB = (H == 128) ? 32 : 16;
    constexpr int NPN  = 64 / LSUB;
    constexpr int DUP  = LSUB / 8;
    int lane = threadIdx.x;
    int sg   = lane / LSUB;
    int l    = lane % LSUB;
    int node = blockIdx.x * NPN + sg;
    if (node >= n) return;
    int base = lane - l;
    int off0 = csr_off[node];
    int deg  = csr_off[node + 1] - off0;

    if (deg == 0) {
        ushort4 hs = *reinterpret_cast<const ushort4*>(hWsb + (size_t)node * H + 4 * l);
        ushort4 ob;
        ob.x = f2b(fmaxf(b2f(hs.x), 0.f));
        ob.y = f2b(fmaxf(b2f(hs.y), 0.f));
        ob.z = f2b(fmaxf(b2f(hs.z), 0.f));
        ob.w = f2b(fmaxf(b2f(hs.w), 0.f));
        *reinterpret_cast<ushort4*>(hout + (size_t)node * H + 4 * l) = ob;
        return;
    }

    float mx = -1e30f;
    for (int i = l; i < deg; i += LSUB) mx = fmaxf(mx, sc_csr[off0 + i]);
    #pragma unroll
    for (int o = LSUB / 2; o > 0; o >>= 1) mx = fmaxf(mx, __shfl_xor(mx, o));
    float ssum = 0.f;
    for (int i = l; i < deg; i += LSUB) ssum += __expf(sc_csr[off0 + i] - mx);
    #pragma unroll
    for (int o = LSUB / 2; o > 0; o >>= 1) ssum += __shfl_xor(ssum, o);
    float invs = 1.f / (ssum + 1e-16f);

    int c8   = l & 7;             // this lane's cea channel
    int jsel = (l >> 3) & (DUP - 1);  // which j-slice this duplicate covers
    float ceac = 0.f;
    float acc4[4] = {0.f, 0.f, 0.f, 0.f};
    for (int j = 0; j < deg; ++j) {
        int pos = off0 + j;
        int sj = esrc[pos];
        float cj = __expf(sc_csr[pos] - mx) * invs;
        unsigned int g = *reinterpret_cast<const unsigned int*>(
            hWm8 + (size_t)sj * H + 4 * l);
        floatx2 lo = __builtin_amdgcn_cvt_pk_f32_fp8(g, false);
        floatx2 hi = __builtin_amdgcn_cvt_pk_f32_fp8(g, true);
        acc4[0] += cj * lo[0];
        acc4[1] += cj * lo[1];
        acc4[2] += cj * hi[0];
        acc4[3] += cj * hi[1];
        if ((j & (DUP - 1)) == jsel) ceac += cj * b2f(ea16[(size_t)pos * 8 + c8]);
    }
    // merge disjoint cea partials across duplicate lanes
    ceac += __shfl_xor(ceac, 8);
    if (LSUB == 32) ceac += __shfl_xor(ceac, 16);
    float cea_k[8];
    #pragma unroll
    for (int k = 0; k < 8; ++k) cea_k[k] = __shfl(ceac, base + k);

    float invdeg = 1.f / (float)deg;
    ushort4 hs = *reinterpret_cast<const ushort4*>(hWsb + (size_t)node * H + 4 * l);
    float sk[4] = {b2f(hs.x), b2f(hs.y), b2f(hs.z), b2f(hs.w)};
    ushort4 ob;
    unsigned short* obp = &ob.x;
    #pragma unroll
    for (int k = 0; k < 4; ++k) {
        int f = 4 * l + k;
        float ew = be[f];
        #pragma unroll
        for (int k8 = 0; k8 < 8; ++k8) ew += cea_k[k8] * We[k8 * H + f];
        float v = (acc4[k] * FP8_INV + ew) * invdeg + sk[k];
        obp[k] = f2b(fmaxf(v, 0.f));
    }
    *reinterpret_cast<ushort4*>(hout + (size_t)node * H + 4 * l) = ob;
}

// ---------------- pooling ----------------
__global__ __launch_bounds__(128)
void pool_sum_kernel(const unsigned short* __restrict__ h, const int* __restrict__ batchh,
                     float* __restrict__ gsum, int n) {
    int f = threadIdx.x;
    int chunk = (n + gridDim.x - 1) / gridDim.x;
    int start = blockIdx.x * chunk;
    int end = min(n, start + chunk);
    if (start >= end) return;
    float acc = 0.f;
    int cur = batchh[start];
    for (int node = start; node < end; ++node) {
        int b = batchh[node];
        if (b != cur) {
            atomicAdd(&gsum[cur * 128 + f], acc);
            acc = 0.f;
            cur = b;
        }
        acc += b2f(h[(size_t)node * 128 + f]);
    }
    atomicAdd(&gsum[cur * 128 + f], acc);
}

// ---------------- classifier (graph count fused via binary search) ----------------
__global__ __launch_bounds__(128)
void classifier_kernel(const float* __restrict__ gsum, const int* __restrict__ batchh, int n,
                       const float* __restrict__ Wc1, const float* __restrict__ bc1,
                       const float* __restrict__ Wc2, const float* __restrict__ bc2,
                       float* __restrict__ out) {
    int b = blockIdx.x;
    int f = threadIdx.x;
    __shared__ float gm[128];
    __shared__ float t1[128];
    __shared__ int cnt;
    if (f == 0) {
        auto lb = [&](int key) {
            int lo = 0, hi = n;
            while (lo < hi) {
                int mid = (lo + hi) >> 1;
                if (batchh[mid] < key) lo = mid + 1; else hi = mid;
            }
            return lo;
        };
        cnt = lb(b + 1) - lb(b);
    }
    __syncthreads();
    float c = (float)max(cnt, 1);
    gm[f] = gsum[b * 128 + f] / c;
    __syncthreads();
    float acc = bc1[f];
    for (int k = 0; k < 128; ++k) acc += gm[k] * Wc1[k * 128 + f];
    t1[f] = fmaxf(acc, 0.f);
    __syncthreads();
    if (f < 4) {
        float o = bc2[f];
        for (int k = 0; k < 128; ++k) o += t1[k] * Wc2[k * 4 + f];
        out[b * 4 + f] = o;
    }
}

extern "C" void kernel_launch(void* const* d_in, const int* in_sizes, int n_in,
                              void* d_out, int out_size, void* d_ws, size_t ws_size,
                              hipStream_t stream) {
    const int* x      = (const int*)d_in[0];
    const int* ei     = (const int*)d_in[1];
    const float* ea   = (const float*)d_in[2];
    const int* batchh = (const int*)d_in[3];
    const float* emb  = (const float*)d_in[4];
    const float* Wm0 = (const float*)d_in[5];  const float* bm0 = (const float*)d_in[6];
    const float* We0 = (const float*)d_in[7];  const float* be0 = (const float*)d_in[8];
    const float* att0 = (const float*)d_in[9];
    const float* Ws0 = (const float*)d_in[10]; const float* bs0 = (const float*)d_in[11];
    const float* Wm1 = (const float*)d_in[12]; const float* bm1 = (const float*)d_in[13];
    const float* We1 = (const float*)d_in[14]; const float* be1 = (const float*)d_in[15];
    const float* att1 = (const float*)d_in[16];
    const float* Ws1 = (const float*)d_in[17]; const float* bs1 = (const float*)d_in[18];
    const float* Wc1 = (const float*)d_in[19]; const float* bc1 = (const float*)d_in[20];
    const float* Wc2 = (const float*)d_in[21]; const float* bc2 = (const float*)d_in[22];

    const int N = in_sizes[0];
    const int E = in_sizes[1] / 2;
    const int G = 64;
    const int H2 = 128;

    char* w = (char*)d_ws;
    auto alloc = [&](size_t bytes) -> void* {
        void* p = (void*)w;
        w += (bytes + 255) & ~(size_t)255;
        return p;
    };
    unsigned short* hbuf = (unsigned short*)alloc((size_t)N * 128 * 2);
    unsigned char* hWm8  = (unsigned char*)alloc((size_t)N * 128);
    unsigned short* hWsb = (unsigned short*)alloc((size_t)N * 128 * 2);
    float* nscore        = (float*)alloc((size_t)N * 4);
    unsigned short* ea16 = (unsigned short*)alloc((size_t)E * 8 * 2);
    float* sc_csr        = (float*)alloc((size_t)E * 4);
    int* esrc            = (int*)alloc((size_t)E * 4);
    int* degcnt          = (int*)alloc((size_t)N * 4);
    int* csroff          = (int*)alloc((size_t)(N + 1) * 4);
    int* cursor          = (int*)alloc((size_t)N * 4);
    float* watt          = (float*)alloc(32 * 4);
    float* gsum          = (float*)alloc((size_t)G * H2 * 4);
    int* blocksum        = (int*)alloc(256 * 4);

    auto cdiv = [](int a, int b) { return (a + b - 1) / b; };
    const int NBLK = cdiv(N, 1024);

    (void)hipMemsetAsync(degcnt, 0, (size_t)N * 4, stream);
    (void)hipMemsetAsync(gsum, 0, (size_t)G * H2 * 4, stream);

    // CSR by dst (hierarchical scan) + CSR-ordered edge streams (ea bf16, fused into fill)
    count_kernel<<<cdiv(E, 256), 256, 0, stream>>>(ei, E, degcnt);
    scan_partial_kernel<<<NBLK, 256, 0, stream>>>(degcnt, blocksum, N);
    scan_blocksum_kernel<<<1, 64, 0, stream>>>(blocksum, csroff, NBLK, N);
    scan_final_kernel<<<NBLK, 256, 0, stream>>>(degcnt, blocksum, csroff, cursor, N);
    fill_kernel<<<cdiv(E, 256), 256, 0, stream>>>(ei, ea, E, cursor, esrc, ea16);
    watt2_kernel<<<2, 64, 0, stream>>>(We0, att0, be0, We1, att1, be1, watt);

    // ---- layer 0: 64 -> 64 ----
    nodelin_kernel<64, 64, false><<<cdiv(N, 64), 256, 0, stream>>>(
        emb, nullptr, x, Wm0, bm0, Ws0, bs0, att0, hWm8, hWsb, nscore, N);
    score_csr_kernel<<<cdiv(E, 256), 256, 0, stream>>>(esrc, ea16, watt, nscore, sc_csr, E);
    agg_kernel<64><<<cdiv(N, 4), 64, 0, stream>>>(csroff, esrc, sc_csr, ea16,
                                                  We0, be0, hWm8, hWsb, hbuf, N);

    // ---- layer 1: 64 -> 128 ----
    nodelin_kernel<128, 32, true><<<cdiv(N, 32), 256, 0, stream>>>(
        nullptr, hbuf, nullptr, Wm1, bm1, Ws1, bs1, att1, hWm8, hWsb, nscore, N);
    score_csr_kernel<<<cdiv(E, 256), 256, 0, stream>>>(esrc, ea16, watt + 16, nscore, sc_csr, E);
    agg_kernel<128><<<cdiv(N, 2), 64, 0, stream>>>(csroff, esrc, sc_csr, ea16,
                                                   We1, be1, hWm8, hWsb, hbuf, N);

    // ---- global mean pool + classifier ----
    pool_sum_kernel<<<512, 128, 0, stream>>>(hbuf, batchh, gsum, N);
    classifier_kernel<<<G, 128, 0, stream>>>(gsum, batchh, N, Wc1, bc1, Wc2, bc2, (float*)d_out);
}

// Round 12
// 388.521 us; speedup vs baseline: 1.0496x; 1.0496x over previous
//
#include <hip/hip_runtime.h>
#include <hip/hip_bf16.h>

#define DEV_INLINE __device__ __forceinline__

static constexpr int WAVE = 64;
static constexpr float FP8_SCALE = 64.0f;
static constexpr float FP8_INV   = 1.0f / 64.0f;

typedef float floatx2 __attribute__((ext_vector_type(2)));

DEV_INLINE float wave_sum(float v) {
    #pragma unroll
    for (int o = 32; o > 0; o >>= 1) v += __shfl_xor(v, o);
    return v;
}
DEV_INLINE float leaky02(float x) { return x > 0.f ? x : 0.2f * x; }
DEV_INLINE unsigned short f2b(float f) {
    __hip_bfloat16 b = __float2bfloat16(f);
    return *reinterpret_cast<unsigned short*>(&b);
}
DEV_INLINE float b2f(unsigned short u) {
    unsigned int x = ((unsigned int)u) << 16;
    return __uint_as_float(x);
}

// ---------------- CSR build ----------------
__global__ void count_kernel(const int* __restrict__ ei, int E, int* __restrict__ deg) {
    int i = blockIdx.x * blockDim.x + threadIdx.x;
    if (i >= E) return;
    atomicAdd(&deg[ei[E + i]], 1);
}

__global__ __launch_bounds__(256)
void scan_partial_kernel(const int* __restrict__ deg, int* __restrict__ blocksum, int n) {
    int t = threadIdx.x;
    int base = blockIdx.x * 1024 + t * 4;
    int s = 0;
    #pragma unroll
    for (int j = 0; j < 4; ++j) { int i = base + j; if (i < n) s += deg[i]; }
    __shared__ int red[4];
    s = (int)wave_sum((float)s);
    if ((t & 63) == 0) red[t >> 6] = s;
    __syncthreads();
    if (t == 0) blocksum[blockIdx.x] = red[0] + red[1] + red[2] + red[3];
}

__global__ __launch_bounds__(64)
void scan_blocksum_kernel(int* __restrict__ blocksum, int* __restrict__ off, int nblk, int n) {
    int lane = threadIdx.x;
    int v = (lane < nblk) ? blocksum[lane] : 0;
    int orig = v;
    #pragma unroll
    for (int o = 1; o < 64; o <<= 1) {
        int u = __shfl_up(v, o);
        if (lane >= o) v += u;
    }
    if (lane < nblk) blocksum[lane] = v - orig;
    if (lane == 63) off[n] = v;
}

__global__ __launch_bounds__(256)
void scan_final_kernel(const int* __restrict__ deg, const int* __restrict__ blockoff,
                       int* __restrict__ off, int* __restrict__ cursor, int n) {
    int t = threadIdx.x, lane = t & 63, wid = t >> 6;
    int base = blockIdx.x * 1024 + t * 4;
    int v[4], s = 0;
    #pragma unroll
    for (int j = 0; j < 4; ++j) {
        int i = base + j;
        v[j] = (i < n) ? deg[i] : 0;
        s += v[j];
    }
    int incl = s;
    #pragma unroll
    for (int o = 1; o < 64; o <<= 1) {
        int u = __shfl_up(incl, o);
        if (lane >= o) incl += u;
    }
    __shared__ int wtot[4];
    if (lane == 63) wtot[wid] = incl;
    __syncthreads();
    int woff = 0;
    for (int w0 = 0; w0 < wid; ++w0) woff += wtot[w0];
    int run = blockoff[blockIdx.x] + woff + incl - s;
    #pragma unroll
    for (int j = 0; j < 4; ++j) {
        int i = base + j;
        if (i < n) { off[i] = run; cursor[i] = run; }
        run += v[j];
    }
}

// fill: CSR src + edge attributes (bf16x8, 16B scatter) in CSR order
__global__ void fill_kernel(const int* __restrict__ ei, const float* __restrict__ ea, int E,
                            int* __restrict__ cursor, int* __restrict__ esrc,
                            unsigned short* __restrict__ ea16) {
    int i = blockIdx.x * blockDim.x + threadIdx.x;
    if (i >= E) return;
    int d = ei[E + i];
    int pos = atomicAdd(&cursor[d], 1);
    esrc[pos] = ei[i];
    const float4* p = reinterpret_cast<const float4*>(ea + (size_t)i * 8);
    float4 a0 = p[0], a1 = p[1];
    ushort4 u0, u1;
    u0.x = f2b(a0.x); u0.y = f2b(a0.y); u0.z = f2b(a0.z); u0.w = f2b(a0.w);
    u1.x = f2b(a1.x); u1.y = f2b(a1.y); u1.z = f2b(a1.z); u1.w = f2b(a1.w);
    ushort4* q = reinterpret_cast<ushort4*>(ea16 + (size_t)pos * 8);
    q[0] = u0; q[1] = u1;
}

// ---------------- both layers' watt in one launch ----------------
__global__ void watt2_kernel(const float* __restrict__ We0, const float* __restrict__ att0,
                             const float* __restrict__ be0,
                             const float* __restrict__ We1, const float* __restrict__ att1,
                             const float* __restrict__ be1,
                             float* __restrict__ watt) {
    int L = blockIdx.x;
    const float* We  = L ? We1 : We0;
    const float* att = L ? att1 : att0;
    const float* be  = L ? be1 : be0;
    int H = L ? 128 : 64;
    int lane = threadIdx.x;
    for (int k = 0; k < 8; ++k) {
        float s = 0.f;
        for (int h = lane; h < H; h += WAVE) s += We[k * H + h] * att[h];
        s = wave_sum(s);
        if (lane == 0) watt[L * 16 + k] = s;
    }
    float s = 0.f;
    for (int h = lane; h < H; h += WAVE) s += be[h] * att[h];
    s = wave_sum(s);
    if (lane == 0) watt[L * 16 + 8] = s;
}

// ---------------- per-layer streaming scores in CSR order ----------------
__global__ void score_csr_kernel(const int* __restrict__ esrc, const unsigned short* __restrict__ ea16,
                                 const float* __restrict__ watt, const float* __restrict__ nscore,
                                 float* __restrict__ sc_csr, int E) {
    int pos = blockIdx.x * blockDim.x + threadIdx.x;
    if (pos >= E) return;
    const ushort4* p = reinterpret_cast<const ushort4*>(ea16 + (size_t)pos * 8);
    ushort4 u0 = p[0], u1 = p[1];
    float s = watt[8];
    s += b2f(u0.x) * watt[0] + b2f(u0.y) * watt[1] + b2f(u0.z) * watt[2] + b2f(u0.w) * watt[3];
    s += b2f(u1.x) * watt[4] + b2f(u1.y) * watt[5] + b2f(u1.z) * watt[6] + b2f(u1.w) * watt[7];
    sc_csr[pos] = leaky02(nscore[esrc[pos]] + s);
}

// ---------------- node linear (LDS-tiled register-blocked GEMM) ----------------
template <int H, int NB, bool INBF16>
__global__ __launch_bounds__(256)
void nodelin_kernel(const float* __restrict__ hf, const unsigned short* __restrict__ hb,
                    const int* __restrict__ xidx,
                    const float* __restrict__ Wm, const float* __restrict__ bm,
                    const float* __restrict__ Ws, const float* __restrict__ bs,
                    const float* __restrict__ att,
                    unsigned char* __restrict__ hWm8, unsigned short* __restrict__ hWsb,
                    float* __restrict__ nscore, int n) {
    constexpr int F4  = H / 4;
    constexpr int NC  = 256 / F4;
    constexpr int NPT = NB / NC;
    constexpr int LDW = 68;
    __shared__ float sh[NB][LDW];
    int n0 = blockIdx.x * NB;
    int tid = threadIdx.x;

    for (int i = tid; i < NB * 16; i += 256) {
        int node = i >> 4, q = i & 15;
        int row = n0 + node;
        float4 v = make_float4(0.f, 0.f, 0.f, 0.f);
        if (row < n) {
            if constexpr (INBF16) {
                ushort4 u = reinterpret_cast<const ushort4*>(hb + (size_t)row * 64)[q];
                v = make_float4(b2f(u.x), b2f(u.y), b2f(u.z), b2f(u.w));
            } else {
                int src = xidx ? xidx[row] : row;
                v = reinterpret_cast<const float4*>(hf + (size_t)src * 64)[q];
            }
        }
        reinterpret_cast<float4*>(&sh[node][0])[q] = v;
    }
    __syncthreads();

    int f4 = (tid % F4) * 4;
    int j0 = tid / F4;
    float4 am[NPT], as[NPT];
    float4 bm4 = *reinterpret_cast<const float4*>(bm + f4);
    float4 bs4 = *reinterpret_cast<const float4*>(bs + f4);
    #pragma unroll
    for (int p = 0; p < NPT; ++p) { am[p] = bm4; as[p] = bs4; }

    for (int k4 = 0; k4 < 16; ++k4) {
        float4 hv[NPT];
        #pragma unroll
        for (int p = 0; p < NPT; ++p)
            hv[p] = reinterpret_cast<const float4*>(&sh[j0 + p * NC][0])[k4];
        #pragma unroll
        for (int kk = 0; kk < 4; ++kk) {
            int k = k4 * 4 + kk;
            float4 wm = *reinterpret_cast<const float4*>(Wm + k * H + f4);
            float4 ws = *reinterpret_cast<const float4*>(Ws + k * H + f4);
            #pragma unroll
            for (int p = 0; p < NPT; ++p) {
                float hk = (&hv[p].x)[kk];
                am[p].x += hk * wm.x; am[p].y += hk * wm.y;
                am[p].z += hk * wm.z; am[p].w += hk * wm.w;
                as[p].x += hk * ws.x; as[p].y += hk * ws.y;
                as[p].z += hk * ws.z; as[p].w += hk * ws.w;
            }
        }
    }

    float4 at4 = *reinterpret_cast<const float4*>(att + f4);
    #pragma unroll
    for (int p = 0; p < NPT; ++p) {
        int row = n0 + j0 + p * NC;
        float sc = am[p].x * at4.x + am[p].y * at4.y + am[p].z * at4.z + am[p].w * at4.w;
        #pragma unroll
        for (int o = 1; o < F4; o <<= 1) sc += __shfl_xor(sc, o);
        if (row < n) {
            int pk = 0;
            pk = __builtin_amdgcn_cvt_pk_fp8_f32(am[p].x * FP8_SCALE, am[p].y * FP8_SCALE, pk, false);
            pk = __builtin_amdgcn_cvt_pk_fp8_f32(am[p].z * FP8_SCALE, am[p].w * FP8_SCALE, pk, true);
            *reinterpret_cast<unsigned int*>(hWm8 + (size_t)row * H + f4) = (unsigned int)pk;
            ushort4 sb;
            sb.x = f2b(as[p].x); sb.y = f2b(as[p].y); sb.z = f2b(as[p].z); sb.w = f2b(as[p].w);
            *reinterpret_cast<ushort4*>(hWsb + (size_t)row * H + f4) = sb;
            if ((tid % F4) == 0) nscore[row] = sc;
        }
    }
}

// ---------------- aggregation: LSUB-lane subgroup per node, register-cached chunks ----
// Per LSUB-chunk: lane l cooperatively loads its edge's (esrc, coef); the j-loop
// broadcasts them by shfl so the only memory op in the hot loop is the fp8 gather.
// cea handled by a slim strided mini-loop (DUP duplicates cover disjoint j-slices).
template <int H>
__global__ __launch_bounds__(256)
void agg_kernel(const int* __restrict__ csr_off,
                const int* __restrict__ esrc, const float* __restrict__ sc_csr,
                const unsigned short* __restrict__ ea16,
                const float* __restrict__ We, const float* __restrict__ be,
                const unsigned char* __restrict__ hWm8, const unsigned short* __restrict__ hWsb,
                unsigned short* __restrict__ hout, int n) {
    constexpr int LSUB = (H == 128) ? 32 : 16;
    constexpr int NPW  = 64 / LSUB;   // nodes per wave
    constexpr int NPB  = NPW * 4;     // nodes per block (4 waves)
    constexpr int DUP  = LSUB / 8;
    int tid  = threadIdx.x;
    int lane = tid & 63;
    int wv   = tid >> 6;
    int sg   = lane / LSUB;
    int l    = lane % LSUB;
    int node = blockIdx.x * NPB + wv * NPW + sg;
    if (node >= n) return;
    int base = lane - l;  // subgroup base lane within the wave
    int off0 = csr_off[node];
    int deg  = csr_off[node + 1] - off0;

    if (deg == 0) {
        ushort4 hs = *reinterpret_cast<const ushort4*>(hWsb + (size_t)node * H + 4 * l);
        ushort4 ob;
        ob.x = f2b(fmaxf(b2f(hs.x), 0.f));
        ob.y = f2b(fmaxf(b2f(hs.y), 0.f));
        ob.z = f2b(fmaxf(b2f(hs.z), 0.f));
        ob.w = f2b(fmaxf(b2f(hs.w), 0.f));
        *reinterpret_cast<ushort4*>(hout + (size_t)node * H + 4 * l) = ob;
        return;
    }

    float mx = -1e30f;
    for (int i = l; i < deg; i += LSUB) mx = fmaxf(mx, sc_csr[off0 + i]);
    #pragma unroll
    for (int o = LSUB / 2; o > 0; o >>= 1) mx = fmaxf(mx, __shfl_xor(mx, o));
    float ssum = 0.f;
    for (int i = l; i < deg; i += LSUB) ssum += __expf(sc_csr[off0 + i] - mx);
    #pragma unroll
    for (int o = LSUB / 2; o > 0; o >>= 1) ssum += __shfl_xor(ssum, o);
    float invs = 1.f / (ssum + 1e-16f);

    int c8   = l & 7;                 // this lane's cea channel
    int jsel = (l >> 3) & (DUP - 1);  // which j-slice this duplicate covers
    float ceac = 0.f;
    float acc4[4] = {0.f, 0.f, 0.f, 0.f};

    for (int c0 = 0; c0 < deg; c0 += LSUB) {
        int cnt = min(LSUB, deg - c0);
        int se = 0;
        float cf = 0.f;
        if (l < cnt) {
            int pos = off0 + c0 + l;
            se = esrc[pos];
            cf = __expf(sc_csr[pos] - mx) * invs;
        }
        // hot loop: shfl-broadcast (sj, cj); sole memory op is the fp8 row gather
        for (int j = 0; j < cnt; ++j) {
            int sj  = __shfl(se, base + j);
            float cj = __shfl(cf, base + j);
            unsigned int g = *reinterpret_cast<const unsigned int*>(
                hWm8 + (size_t)sj * H + 4 * l);
            floatx2 lo = __builtin_amdgcn_cvt_pk_f32_fp8(g, false);
            floatx2 hi = __builtin_amdgcn_cvt_pk_f32_fp8(g, true);
            acc4[0] += cj * lo[0];
            acc4[1] += cj * lo[1];
            acc4[2] += cj * hi[0];
            acc4[3] += cj * hi[1];
        }
        // cea mini-loop over this duplicate's disjoint j-slice
        for (int j = jsel; j < cnt; j += DUP) {
            float cj = __shfl(cf, base + j);
            ceac += cj * b2f(ea16[(size_t)(off0 + c0 + j) * 8 + c8]);
        }
    }
    ceac += __shfl_xor(ceac, 8);
    if (LSUB == 32) ceac += __shfl_xor(ceac, 16);
    float cea_k[8];
    #pragma unroll
    for (int k = 0; k < 8; ++k) cea_k[k] = __shfl(ceac, base + k);

    float invdeg = 1.f / (float)deg;
    ushort4 hs = *reinterpret_cast<const ushort4*>(hWsb + (size_t)node * H + 4 * l);
    float sk[4] = {b2f(hs.x), b2f(hs.y), b2f(hs.z), b2f(hs.w)};
    ushort4 ob;
    unsigned short* obp = &ob.x;
    #pragma unroll
    for (int k = 0; k < 4; ++k) {
        int f = 4 * l + k;
        float ew = be[f];
        #pragma unroll
        for (int k8 = 0; k8 < 8; ++k8) ew += cea_k[k8] * We[k8 * H + f];
        float v = (acc4[k] * FP8_INV + ew) * invdeg + sk[k];
        obp[k] = f2b(fmaxf(v, 0.f));
    }
    *reinterpret_cast<ushort4*>(hout + (size_t)node * H + 4 * l) = ob;
}

// ---------------- pooling ----------------
__global__ __launch_bounds__(128)
void pool_sum_kernel(const unsigned short* __restrict__ h, const int* __restrict__ batchh,
                     float* __restrict__ gsum, int n) {
    int f = threadIdx.x;
    int chunk = (n + gridDim.x - 1) / gridDim.x;
    int start = blockIdx.x * chunk;
    int end = min(n, start + chunk);
    if (start >= end) return;
    float acc = 0.f;
    int cur = batchh[start];
    for (int node = start; node < end; ++node) {
        int b = batchh[node];
        if (b != cur) {
            atomicAdd(&gsum[cur * 128 + f], acc);
            acc = 0.f;
            cur = b;
        }
        acc += b2f(h[(size_t)node * 128 + f]);
    }
    atomicAdd(&gsum[cur * 128 + f], acc);
}

// ---------------- classifier (graph count fused via binary search) ----------------
__global__ __launch_bounds__(128)
void classifier_kernel(const float* __restrict__ gsum, const int* __restrict__ batchh, int n,
                       const float* __restrict__ Wc1, const float* __restrict__ bc1,
                       const float* __restrict__ Wc2, const float* __restrict__ bc2,
                       float* __restrict__ out) {
    int b = blockIdx.x;
    int f = threadIdx.x;
    __shared__ float gm[128];
    __shared__ float t1[128];
    __shared__ int cnt;
    if (f == 0) {
        auto lb = [&](int key) {
            int lo = 0, hi = n;
            while (lo < hi) {
                int mid = (lo + hi) >> 1;
                if (batchh[mid] < key) lo = mid + 1; else hi = mid;
            }
            return lo;
        };
        cnt = lb(b + 1) - lb(b);
    }
    __syncthreads();
    float c = (float)max(cnt, 1);
    gm[f] = gsum[b * 128 + f] / c;
    __syncthreads();
    float acc = bc1[f];
    for (int k = 0; k < 128; ++k) acc += gm[k] * Wc1[k * 128 + f];
    t1[f] = fmaxf(acc, 0.f);
    __syncthreads();
    if (f < 4) {
        float o = bc2[f];
        for (int k = 0; k < 128; ++k) o += t1[k] * Wc2[k * 4 + f];
        out[b * 4 + f] = o;
    }
}

extern "C" void kernel_launch(void* const* d_in, const int* in_sizes, int n_in,
                              void* d_out, int out_size, void* d_ws, size_t ws_size,
                              hipStream_t stream) {
    const int* x      = (const int*)d_in[0];
    const int* ei     = (const int*)d_in[1];
    const float* ea   = (const float*)d_in[2];
    const int* batchh = (const int*)d_in[3];
    const float* emb  = (const float*)d_in[4];
    const float* Wm0 = (const float*)d_in[5];  const float* bm0 = (const float*)d_in[6];
    const float* We0 = (const float*)d_in[7];  const float* be0 = (const float*)d_in[8];
    const float* att0 = (const float*)d_in[9];
    const float* Ws0 = (const float*)d_in[10]; const float* bs0 = (const float*)d_in[11];
    const float* Wm1 = (const float*)d_in[12]; const float* bm1 = (const float*)d_in[13];
    const float* We1 = (const float*)d_in[14]; const float* be1 = (const float*)d_in[15];
    const float* att1 = (const float*)d_in[16];
    const float* Ws1 = (const float*)d_in[17]; const float* bs1 = (const float*)d_in[18];
    const float* Wc1 = (const float*)d_in[19]; const float* bc1 = (const float*)d_in[20];
    const float* Wc2 = (const float*)d_in[21]; const float* bc2 = (const float*)d_in[22];

    const int N = in_sizes[0];
    const int E = in_sizes[1] / 2;
    const int G = 64;
    const int H2 = 128;

    char* w = (char*)d_ws;
    auto alloc = [&](size_t bytes) -> void* {
        void* p = (void*)w;
        w += (bytes + 255) & ~(size_t)255;
        return p;
    };
    unsigned short* hbuf = (unsigned short*)alloc((size_t)N * 128 * 2);
    unsigned char* hWm8  = (unsigned char*)alloc((size_t)N * 128);
    unsigned short* hWsb = (unsigned short*)alloc((size_t)N * 128 * 2);
    float* nscore        = (float*)alloc((size_t)N * 4);
    unsigned short* ea16 = (unsigned short*)alloc((size_t)E * 8 * 2);
    float* sc_csr        = (float*)alloc((size_t)E * 4);
    int* esrc            = (int*)alloc((size_t)E * 4);
    int* degcnt          = (int*)alloc((size_t)N * 4);
    int* csroff          = (int*)alloc((size_t)(N + 1) * 4);
    int* cursor          = (int*)alloc((size_t)N * 4);
    float* watt          = (float*)alloc(32 * 4);
    float* gsum          = (float*)alloc((size_t)G * H2 * 4);
    int* blocksum        = (int*)alloc(256 * 4);

    auto cdiv = [](int a, int b) { return (a + b - 1) / b; };
    const int NBLK = cdiv(N, 1024);

    (void)hipMemsetAsync(degcnt, 0, (size_t)N * 4, stream);
    (void)hipMemsetAsync(gsum, 0, (size_t)G * H2 * 4, stream);

    // CSR by dst (hierarchical scan) + CSR-ordered edge streams (ea bf16, fused into fill)
    count_kernel<<<cdiv(E, 256), 256, 0, stream>>>(ei, E, degcnt);
    scan_partial_kernel<<<NBLK, 256, 0, stream>>>(degcnt, blocksum, N);
    scan_blocksum_kernel<<<1, 64, 0, stream>>>(blocksum, csroff, NBLK, N);
    scan_final_kernel<<<NBLK, 256, 0, stream>>>(degcnt, blocksum, csroff, cursor, N);
    fill_kernel<<<cdiv(E, 256), 256, 0, stream>>>(ei, ea, E, cursor, esrc, ea16);
    watt2_kernel<<<2, 64, 0, stream>>>(We0, att0, be0, We1, att1, be1, watt);

    // ---- layer 0: 64 -> 64 ----
    nodelin_kernel<64, 64, false><<<cdiv(N, 64), 256, 0, stream>>>(
        emb, nullptr, x, Wm0, bm0, Ws0, bs0, att0, hWm8, hWsb, nscore, N);
    score_csr_kernel<<<cdiv(E, 256), 256, 0, stream>>>(esrc, ea16, watt, nscore, sc_csr, E);
    agg_kernel<64><<<cdiv(N, 16), 256, 0, stream>>>(csroff, esrc, sc_csr, ea16,
                                                    We0, be0, hWm8, hWsb, hbuf, N);

    // ---- layer 1: 64 -> 128 ----
    nodelin_kernel<128, 32, true><<<cdiv(N, 32), 256, 0, stream>>>(
        nullptr, hbuf, nullptr, Wm1, bm1, Ws1, bs1, att1, hWm8, hWsb, nscore, N);
    score_csr_kernel<<<cdiv(E, 256), 256, 0, stream>>>(esrc, ea16, watt + 16, nscore, sc_csr, E);
    agg_kernel<128><<<cdiv(N, 8), 256, 0, stream>>>(csroff, esrc, sc_csr, ea16,
                                                    We1, be1, hWm8, hWsb, hbuf, N);

    // ---- global mean pool + classifier ----
    pool_sum_kernel<<<512, 128, 0, stream>>>(hbuf, batchh, gsum, N);
    classifier_kernel<<<G, 128, 0, stream>>>(gsum, batchh, N, Wc1, bc1, Wc2, bc2, (float*)d_out);
}

// Round 13
// 369.584 us; speedup vs baseline: 1.1034x; 1.0512x over previous
//
#include <hip/hip_runtime.h>
#include <hip/hip_bf16.h>

#define DEV_INLINE __device__ __forceinline__

static constexpr int WAVE = 64;
static constexpr float FP8_SCALE = 64.0f;   // hWm8 message table scale
static constexpr float FP8_INV   = 1.0f / 64.0f;
static constexpr float EA_SCALE  = 8.0f;    // ea fp8 scale
static constexpr float EA_INV    = 1.0f / 8.0f;

typedef float floatx2 __attribute__((ext_vector_type(2)));

DEV_INLINE float wave_sum(float v) {
    #pragma unroll
    for (int o = 32; o > 0; o >>= 1) v += __shfl_xor(v, o);
    return v;
}
DEV_INLINE float leaky02(float x) { return x > 0.f ? x : 0.2f * x; }
DEV_INLINE unsigned short f2b(float f) {
    __hip_bfloat16 b = __float2bfloat16(f);
    return *reinterpret_cast<unsigned short*>(&b);
}
DEV_INLINE float b2f(unsigned short u) {
    unsigned int x = ((unsigned int)u) << 16;
    return __uint_as_float(x);
}

// ---------------- CSR build ----------------
__global__ void count_kernel(const int* __restrict__ ei, int E, int* __restrict__ deg) {
    int i = blockIdx.x * blockDim.x + threadIdx.x;
    if (i >= E) return;
    atomicAdd(&deg[ei[E + i]], 1);
}

__global__ __launch_bounds__(256)
void scan_partial_kernel(const int* __restrict__ deg, int* __restrict__ blocksum, int n) {
    int t = threadIdx.x;
    int base = blockIdx.x * 1024 + t * 4;
    int s = 0;
    #pragma unroll
    for (int j = 0; j < 4; ++j) { int i = base + j; if (i < n) s += deg[i]; }
    __shared__ int red[4];
    s = (int)wave_sum((float)s);
    if ((t & 63) == 0) red[t >> 6] = s;
    __syncthreads();
    if (t == 0) blocksum[blockIdx.x] = red[0] + red[1] + red[2] + red[3];
}

__global__ __launch_bounds__(64)
void scan_blocksum_kernel(int* __restrict__ blocksum, int* __restrict__ off, int nblk, int n) {
    int lane = threadIdx.x;
    int v = (lane < nblk) ? blocksum[lane] : 0;
    int orig = v;
    #pragma unroll
    for (int o = 1; o < 64; o <<= 1) {
        int u = __shfl_up(v, o);
        if (lane >= o) v += u;
    }
    if (lane < nblk) blocksum[lane] = v - orig;
    if (lane == 63) off[n] = v;
}

__global__ __launch_bounds__(256)
void scan_final_kernel(const int* __restrict__ deg, const int* __restrict__ blockoff,
                       int* __restrict__ off, int* __restrict__ cursor, int n) {
    int t = threadIdx.x, lane = t & 63, wid = t >> 6;
    int base = blockIdx.x * 1024 + t * 4;
    int v[4], s = 0;
    #pragma unroll
    for (int j = 0; j < 4; ++j) {
        int i = base + j;
        v[j] = (i < n) ? deg[i] : 0;
        s += v[j];
    }
    int incl = s;
    #pragma unroll
    for (int o = 1; o < 64; o <<= 1) {
        int u = __shfl_up(incl, o);
        if (lane >= o) incl += u;
    }
    __shared__ int wtot[4];
    if (lane == 63) wtot[wid] = incl;
    __syncthreads();
    int woff = 0;
    for (int w0 = 0; w0 < wid; ++w0) woff += wtot[w0];
    int run = blockoff[blockIdx.x] + woff + incl - s;
    #pragma unroll
    for (int j = 0; j < 4; ++j) {
        int i = base + j;
        if (i < n) { off[i] = run; cursor[i] = run; }
        run += v[j];
    }
}

// ---------------- both layers' watt in one launch (before fill) ----------------
__global__ void watt2_kernel(const float* __restrict__ We0, const float* __restrict__ att0,
                             const float* __restrict__ be0,
                             const float* __restrict__ We1, const float* __restrict__ att1,
                             const float* __restrict__ be1,
                             float* __restrict__ watt) {
    int L = blockIdx.x;
    const float* We  = L ? We1 : We0;
    const float* att = L ? att1 : att0;
    const float* be  = L ? be1 : be0;
    int H = L ? 128 : 64;
    int lane = threadIdx.x;
    for (int k = 0; k < 8; ++k) {
        float s = 0.f;
        for (int h = lane; h < H; h += WAVE) s += We[k * H + h] * att[h];
        s = wave_sum(s);
        if (lane == 0) watt[L * 16 + k] = s;
    }
    float s = 0.f;
    for (int h = lane; h < H; h += WAVE) s += be[h] * att[h];
    s = wave_sum(s);
    if (lane == 0) watt[L * 16 + 8] = s;
}

// ---------------- fill: ONE 16B packed scatter per edge ----------------
// packed[pos] = { esrc:int, eawatt0:bf16 | eawatt1<<16, ea fp8x4 lo, ea fp8x4 hi }
__global__ void fill_kernel(const int* __restrict__ ei, const float* __restrict__ ea, int E,
                            const float* __restrict__ watt,
                            int* __restrict__ cursor, uint4* __restrict__ packed) {
    int i = blockIdx.x * blockDim.x + threadIdx.x;
    if (i >= E) return;
    int d = ei[E + i];
    int src = ei[i];
    const float4* p = reinterpret_cast<const float4*>(ea + (size_t)i * 8);
    float4 a0 = p[0], a1 = p[1];
    float e0 = watt[8]
             + a0.x * watt[0] + a0.y * watt[1] + a0.z * watt[2] + a0.w * watt[3]
             + a1.x * watt[4] + a1.y * watt[5] + a1.z * watt[6] + a1.w * watt[7];
    float e1 = watt[24]
             + a0.x * watt[16] + a0.y * watt[17] + a0.z * watt[18] + a0.w * watt[19]
             + a1.x * watt[20] + a1.y * watt[21] + a1.z * watt[22] + a1.w * watt[23];
    int lo = 0, hi = 0;
    lo = __builtin_amdgcn_cvt_pk_fp8_f32(a0.x * EA_SCALE, a0.y * EA_SCALE, lo, false);
    lo = __builtin_amdgcn_cvt_pk_fp8_f32(a0.z * EA_SCALE, a0.w * EA_SCALE, lo, true);
    hi = __builtin_amdgcn_cvt_pk_fp8_f32(a1.x * EA_SCALE, a1.y * EA_SCALE, hi, false);
    hi = __builtin_amdgcn_cvt_pk_fp8_f32(a1.z * EA_SCALE, a1.w * EA_SCALE, hi, true);
    int pos = atomicAdd(&cursor[d], 1);
    uint4 pk;
    pk.x = (unsigned int)src;
    pk.y = (unsigned int)f2b(e0) | ((unsigned int)f2b(e1) << 16);
    pk.z = (unsigned int)lo;
    pk.w = (unsigned int)hi;
    packed[pos] = pk;
}

// ---------------- node linear (LDS-tiled register-blocked GEMM) ----------------
template <int H, int NB, bool INBF16>
__global__ __launch_bounds__(256)
void nodelin_kernel(const float* __restrict__ hf, const unsigned short* __restrict__ hb,
                    const int* __restrict__ xidx,
                    const float* __restrict__ Wm, const float* __restrict__ bm,
                    const float* __restrict__ Ws, const float* __restrict__ bs,
                    const float* __restrict__ att,
                    unsigned char* __restrict__ hWm8, unsigned short* __restrict__ hWsb,
                    float* __restrict__ nscore, int n) {
    constexpr int F4  = H / 4;
    constexpr int NC  = 256 / F4;
    constexpr int NPT = NB / NC;
    constexpr int LDW = 68;
    __shared__ float sh[NB][LDW];
    int n0 = blockIdx.x * NB;
    int tid = threadIdx.x;

    for (int i = tid; i < NB * 16; i += 256) {
        int node = i >> 4, q = i & 15;
        int row = n0 + node;
        float4 v = make_float4(0.f, 0.f, 0.f, 0.f);
        if (row < n) {
            if constexpr (INBF16) {
                ushort4 u = reinterpret_cast<const ushort4*>(hb + (size_t)row * 64)[q];
                v = make_float4(b2f(u.x), b2f(u.y), b2f(u.z), b2f(u.w));
            } else {
                int src = xidx ? xidx[row] : row;
                v = reinterpret_cast<const float4*>(hf + (size_t)src * 64)[q];
            }
        }
        reinterpret_cast<float4*>(&sh[node][0])[q] = v;
    }
    __syncthreads();

    int f4 = (tid % F4) * 4;
    int j0 = tid / F4;
    float4 am[NPT], as[NPT];
    float4 bm4 = *reinterpret_cast<const float4*>(bm + f4);
    float4 bs4 = *reinterpret_cast<const float4*>(bs + f4);
    #pragma unroll
    for (int p = 0; p < NPT; ++p) { am[p] = bm4; as[p] = bs4; }

    for (int k4 = 0; k4 < 16; ++k4) {
        float4 hv[NPT];
        #pragma unroll
        for (int p = 0; p < NPT; ++p)
            hv[p] = reinterpret_cast<const float4*>(&sh[j0 + p * NC][0])[k4];
        #pragma unroll
        for (int kk = 0; kk < 4; ++kk) {
            int k = k4 * 4 + kk;
            float4 wm = *reinterpret_cast<const float4*>(Wm + k * H + f4);
            float4 ws = *reinterpret_cast<const float4*>(Ws + k * H + f4);
            #pragma unroll
            for (int p = 0; p < NPT; ++p) {
                float hk = (&hv[p].x)[kk];
                am[p].x += hk * wm.x; am[p].y += hk * wm.y;
                am[p].z += hk * wm.z; am[p].w += hk * wm.w;
                as[p].x += hk * ws.x; as[p].y += hk * ws.y;
                as[p].z += hk * ws.z; as[p].w += hk * ws.w;
            }
        }
    }

    float4 at4 = *reinterpret_cast<const float4*>(att + f4);
    #pragma unroll
    for (int p = 0; p < NPT; ++p) {
        int row = n0 + j0 + p * NC;
        float sc = am[p].x * at4.x + am[p].y * at4.y + am[p].z * at4.z + am[p].w * at4.w;
        #pragma unroll
        for (int o = 1; o < F4; o <<= 1) sc += __shfl_xor(sc, o);
        if (row < n) {
            int pk = 0;
            pk = __builtin_amdgcn_cvt_pk_fp8_f32(am[p].x * FP8_SCALE, am[p].y * FP8_SCALE, pk, false);
            pk = __builtin_amdgcn_cvt_pk_fp8_f32(am[p].z * FP8_SCALE, am[p].w * FP8_SCALE, pk, true);
            *reinterpret_cast<unsigned int*>(hWm8 + (size_t)row * H + f4) = (unsigned int)pk;
            ushort4 sb;
            sb.x = f2b(as[p].x); sb.y = f2b(as[p].y); sb.z = f2b(as[p].z); sb.w = f2b(as[p].w);
            *reinterpret_cast<ushort4*>(hWsb + (size_t)row * H + f4) = sb;
            if ((tid % F4) == 0) nscore[row] = sc;
        }
    }
}

// ---------------- aggregation: packed-edge struct, register-cached chunks ----------------
// Lane l of an LSUB subgroup owns edge chunk slot l: one uint4 sequential load gives
// esrc, eawatt (bf16, layer half), and the full fp8 ea vector. sc computed inline
// (nscore is an L2-hot 200KB table). Hot gather loop: shfl-broadcast (sj,cj) only.
template <int H, int L>
__global__ __launch_bounds__(256)
void agg_kernel(const int* __restrict__ csr_off, const uint4* __restrict__ packed,
                const float* __restrict__ nscore,
                const float* __restrict__ We, const float* __restrict__ be,
                const unsigned char* __restrict__ hWm8, const unsigned short* __restrict__ hWsb,
                unsigned short* __restrict__ hout, int n) {
    constexpr int LSUB = (H == 128) ? 32 : 16;
    constexpr int NPW  = 64 / LSUB;
    constexpr int NPB  = NPW * 4;
    constexpr int MAXC = 64 / LSUB;  // cached chunks cover deg <= 64 (~always)
    int tid  = threadIdx.x;
    int lane = tid & 63;
    int wv   = tid >> 6;
    int sg   = lane / LSUB;
    int l    = lane % LSUB;
    int node = blockIdx.x * NPB + wv * NPW + sg;
    if (node >= n) return;
    int base = lane - l;
    int off0 = csr_off[node];
    int deg  = csr_off[node + 1] - off0;

    if (deg == 0) {
        ushort4 hs = *reinterpret_cast<const ushort4*>(hWsb + (size_t)node * H + 4 * l);
        ushort4 ob;
        ob.x = f2b(fmaxf(b2f(hs.x), 0.f));
        ob.y = f2b(fmaxf(b2f(hs.y), 0.f));
        ob.z = f2b(fmaxf(b2f(hs.z), 0.f));
        ob.w = f2b(fmaxf(b2f(hs.w), 0.f));
        *reinterpret_cast<ushort4*>(hout + (size_t)node * H + 4 * l) = ob;
        return;
    }

    float acc4[4] = {0.f, 0.f, 0.f, 0.f};
    float cea8[8] = {0.f, 0.f, 0.f, 0.f, 0.f, 0.f, 0.f, 0.f};

    if (deg <= MAXC * LSUB) {
        // ---- cached path (deg <= 64) ----
        int se[MAXC];
        float cf[MAXC];
        unsigned int g0[MAXC], g1[MAXC];
        float mx = -1e30f;
        #pragma unroll
        for (int c = 0; c < MAXC; ++c) {
            int i = c * LSUB + l;
            se[c] = 0; g0[c] = 0; g1[c] = 0;
            float sc = -1e30f;
            if (i < deg) {
                uint4 pk = packed[off0 + i];
                se[c] = (int)pk.x;
                float eaw = b2f((unsigned short)((pk.y >> (L * 16)) & 0xffff));
                sc = leaky02(nscore[se[c]] + eaw);
                g0[c] = pk.z; g1[c] = pk.w;
            }
            cf[c] = sc;
            mx = fmaxf(mx, sc);
        }
        #pragma unroll
        for (int o = LSUB / 2; o > 0; o >>= 1) mx = fmaxf(mx, __shfl_xor(mx, o));
        float ssum = 0.f;
        #pragma unroll
        for (int c = 0; c < MAXC; ++c) {
            int i = c * LSUB + l;
            float e = (i < deg) ? __expf(cf[c] - mx) : 0.f;
            cf[c] = e;
            ssum += e;
        }
        #pragma unroll
        for (int o = LSUB / 2; o > 0; o >>= 1) ssum += __shfl_xor(ssum, o);
        float invs = 1.f / (ssum + 1e-16f);

        #pragma unroll
        for (int c = 0; c < MAXC; ++c) {
            cf[c] *= invs;
            // per-lane cea: own edge's fp8 ea weighted by own coef
            float cj = cf[c];
            if (cj > 0.f) {
                floatx2 p0 = __builtin_amdgcn_cvt_pk_f32_fp8(g0[c], false);
                floatx2 p1 = __builtin_amdgcn_cvt_pk_f32_fp8(g0[c], true);
                floatx2 p2 = __builtin_amdgcn_cvt_pk_f32_fp8(g1[c], false);
                floatx2 p3 = __builtin_amdgcn_cvt_pk_f32_fp8(g1[c], true);
                cea8[0] += cj * p0[0]; cea8[1] += cj * p0[1];
                cea8[2] += cj * p1[0]; cea8[3] += cj * p1[1];
                cea8[4] += cj * p2[0]; cea8[5] += cj * p2[1];
                cea8[6] += cj * p3[0]; cea8[7] += cj * p3[1];
            }
        }
        // hot gather loop
        #pragma unroll
        for (int c = 0; c < MAXC; ++c) {
            int cnt = min(LSUB, deg - c * LSUB);
            for (int j = 0; j < cnt; ++j) {
                int sj  = __shfl(se[c], base + j);
                float cj = __shfl(cf[c], base + j);
                unsigned int g = *reinterpret_cast<const unsigned int*>(
                    hWm8 + (size_t)sj * H + 4 * l);
                floatx2 lo = __builtin_amdgcn_cvt_pk_f32_fp8(g, false);
                floatx2 hi = __builtin_amdgcn_cvt_pk_f32_fp8(g, true);
                acc4[0] += cj * lo[0];
                acc4[1] += cj * lo[1];
                acc4[2] += cj * hi[0];
                acc4[3] += cj * hi[1];
            }
            if ((c + 1) * LSUB >= deg) break;
        }
    } else {
        // ---- streaming fallback (deg > 64; ~never) ----
        float mx = -1e30f;
        for (int i = l; i < deg; i += LSUB) {
            uint4 pk = packed[off0 + i];
            float eaw = b2f((unsigned short)((pk.y >> (L * 16)) & 0xffff));
            mx = fmaxf(mx, leaky02(nscore[(int)pk.x] + eaw));
        }
        #pragma unroll
        for (int o = LSUB / 2; o > 0; o >>= 1) mx = fmaxf(mx, __shfl_xor(mx, o));
        float ssum = 0.f;
        for (int i = l; i < deg; i += LSUB) {
            uint4 pk = packed[off0 + i];
            float eaw = b2f((unsigned short)((pk.y >> (L * 16)) & 0xffff));
            ssum += __expf(leaky02(nscore[(int)pk.x] + eaw) - mx);
        }
        #pragma unroll
        for (int o = LSUB / 2; o > 0; o >>= 1) ssum += __shfl_xor(ssum, o);
        float invs = 1.f / (ssum + 1e-16f);

        for (int c0 = 0; c0 < deg; c0 += LSUB) {
            int cnt = min(LSUB, deg - c0);
            int se = 0;
            float cf = 0.f;
            if (l < cnt) {
                uint4 pk = packed[off0 + c0 + l];
                se = (int)pk.x;
                float eaw = b2f((unsigned short)((pk.y >> (L * 16)) & 0xffff));
                cf = __expf(leaky02(nscore[se] + eaw) - mx) * invs;
                floatx2 p0 = __builtin_amdgcn_cvt_pk_f32_fp8(pk.z, false);
                floatx2 p1 = __builtin_amdgcn_cvt_pk_f32_fp8(pk.z, true);
                floatx2 p2 = __builtin_amdgcn_cvt_pk_f32_fp8(pk.w, false);
                floatx2 p3 = __builtin_amdgcn_cvt_pk_f32_fp8(pk.w, true);
                cea8[0] += cf * p0[0]; cea8[1] += cf * p0[1];
                cea8[2] += cf * p1[0]; cea8[3] += cf * p1[1];
                cea8[4] += cf * p2[0]; cea8[5] += cf * p2[1];
                cea8[6] += cf * p3[0]; cea8[7] += cf * p3[1];
            }
            for (int j = 0; j < cnt; ++j) {
                int sj  = __shfl(se, base + j);
                float cj = __shfl(cf, base + j);
                unsigned int g = *reinterpret_cast<const unsigned int*>(
                    hWm8 + (size_t)sj * H + 4 * l);
                floatx2 lo = __builtin_amdgcn_cvt_pk_f32_fp8(g, false);
                floatx2 hi = __builtin_amdgcn_cvt_pk_f32_fp8(g, true);
                acc4[0] += cj * lo[0];
                acc4[1] += cj * lo[1];
                acc4[2] += cj * hi[0];
                acc4[3] += cj * hi[1];
            }
        }
    }

    // reduce cea8 across the subgroup (each lane holds partials for all 8 channels)
    #pragma unroll
    for (int k = 0; k < 8; ++k) {
        float v = cea8[k];
        #pragma unroll
        for (int o = LSUB / 2; o > 0; o >>= 1) v += __shfl_xor(v, o);
        cea8[k] = v * EA_INV;
    }

    float invdeg = 1.f / (float)deg;
    ushort4 hs = *reinterpret_cast<const ushort4*>(hWsb + (size_t)node * H + 4 * l);
    float sk[4] = {b2f(hs.x), b2f(hs.y), b2f(hs.z), b2f(hs.w)};
    ushort4 ob;
    unsigned short* obp = &ob.x;
    #pragma unroll
    for (int k = 0; k < 4; ++k) {
        int f = 4 * l + k;
        float ew = be[f];
        #pragma unroll
        for (int k8 = 0; k8 < 8; ++k8) ew += cea8[k8] * We[k8 * H + f];
        float v = (acc4[k] * FP8_INV + ew) * invdeg + sk[k];
        obp[k] = f2b(fmaxf(v, 0.f));
    }
    *reinterpret_cast<ushort4*>(hout + (size_t)node * H + 4 * l) = ob;
}

// ---------------- pooling ----------------
__global__ __launch_bounds__(128)
void pool_sum_kernel(const unsigned short* __restrict__ h, const int* __restrict__ batchh,
                     float* __restrict__ gsum, int n) {
    int f = threadIdx.x;
    int chunk = (n + gridDim.x - 1) / gridDim.x;
    int start = blockIdx.x * chunk;
    int end = min(n, start + chunk);
    if (start >= end) return;
    float acc = 0.f;
    int cur = batchh[start];
    for (int node = start; node < end; ++node) {
        int b = batchh[node];
        if (b != cur) {
            atomicAdd(&gsum[cur * 128 + f], acc);
            acc = 0.f;
            cur = b;
        }
        acc += b2f(h[(size_t)node * 128 + f]);
    }
    atomicAdd(&gsum[cur * 128 + f], acc);
}

// ---------------- classifier (graph count fused via binary search) ----------------
__global__ __launch_bounds__(128)
void classifier_kernel(const float* __restrict__ gsum, const int* __restrict__ batchh, int n,
                       const float* __restrict__ Wc1, const float* __restrict__ bc1,
                       const float* __restrict__ Wc2, const float* __restrict__ bc2,
                       float* __restrict__ out) {
    int b = blockIdx.x;
    int f = threadIdx.x;
    __shared__ float gm[128];
    __shared__ float t1[128];
    __shared__ int cnt;
    if (f == 0) {
        auto lb = [&](int key) {
            int lo = 0, hi = n;
            while (lo < hi) {
                int mid = (lo + hi) >> 1;
                if (batchh[mid] < key) lo = mid + 1; else hi = mid;
            }
            return lo;
        };
        cnt = lb(b + 1) - lb(b);
    }
    __syncthreads();
    float c = (float)max(cnt, 1);
    gm[f] = gsum[b * 128 + f] / c;
    __syncthreads();
    float acc = bc1[f];
    for (int k = 0; k < 128; ++k) acc += gm[k] * Wc1[k * 128 + f];
    t1[f] = fmaxf(acc, 0.f);
    __syncthreads();
    if (f < 4) {
        float o = bc2[f];
        for (int k = 0; k < 128; ++k) o += t1[k] * Wc2[k * 4 + f];
        out[b * 4 + f] = o;
    }
}

extern "C" void kernel_launch(void* const* d_in, const int* in_sizes, int n_in,
                              void* d_out, int out_size, void* d_ws, size_t ws_size,
                              hipStream_t stream) {
    const int* x      = (const int*)d_in[0];
    const int* ei     = (const int*)d_in[1];
    const float* ea   = (const float*)d_in[2];
    const int* batchh = (const int*)d_in[3];
    const float* emb  = (const float*)d_in[4];
    const float* Wm0 = (const float*)d_in[5];  const float* bm0 = (const float*)d_in[6];
    const float* We0 = (const float*)d_in[7];  const float* be0 = (const float*)d_in[8];
    const float* att0 = (const float*)d_in[9];
    const float* Ws0 = (const float*)d_in[10]; const float* bs0 = (const float*)d_in[11];
    const float* Wm1 = (const float*)d_in[12]; const float* bm1 = (const float*)d_in[13];
    const float* We1 = (const float*)d_in[14]; const float* be1 = (const float*)d_in[15];
    const float* att1 = (const float*)d_in[16];
    const float* Ws1 = (const float*)d_in[17]; const float* bs1 = (const float*)d_in[18];
    const float* Wc1 = (const float*)d_in[19]; const float* bc1 = (const float*)d_in[20];
    const float* Wc2 = (const float*)d_in[21]; const float* bc2 = (const float*)d_in[22];

    const int N = in_sizes[0];
    const int E = in_sizes[1] / 2;
    const int G = 64;
    const int H2 = 128;

    char* w = (char*)d_ws;
    auto alloc = [&](size_t bytes) -> void* {
        void* p = (void*)w;
        w += (bytes + 255) & ~(size_t)255;
        return p;
    };
    unsigned short* hbuf = (unsigned short*)alloc((size_t)N * 128 * 2);
    unsigned char* hWm8  = (unsigned char*)alloc((size_t)N * 128);
    unsigned short* hWsb = (unsigned short*)alloc((size_t)N * 128 * 2);
    float* nscore        = (float*)alloc((size_t)N * 4);
    uint4* packed        = (uint4*)alloc((size_t)E * 16);
    int* degcnt          = (int*)alloc((size_t)N * 4);
    int* csroff          = (int*)alloc((size_t)(N + 1) * 4);
    int* cursor          = (int*)alloc((size_t)N * 4);
    float* watt          = (float*)alloc(32 * 4);
    float* gsum          = (float*)alloc((size_t)G * H2 * 4);
    int* blocksum        = (int*)alloc(256 * 4);

    auto cdiv = [](int a, int b) { return (a + b - 1) / b; };
    const int NBLK = cdiv(N, 1024);

    (void)hipMemsetAsync(degcnt, 0, (size_t)N * 4, stream);
    (void)hipMemsetAsync(gsum, 0, (size_t)G * H2 * 4, stream);

    // CSR by dst + single-store packed edge stream
    count_kernel<<<cdiv(E, 256), 256, 0, stream>>>(ei, E, degcnt);
    scan_partial_kernel<<<NBLK, 256, 0, stream>>>(degcnt, blocksum, N);
    scan_blocksum_kernel<<<1, 64, 0, stream>>>(blocksum, csroff, NBLK, N);
    scan_final_kernel<<<NBLK, 256, 0, stream>>>(degcnt, blocksum, csroff, cursor, N);
    watt2_kernel<<<2, 64, 0, stream>>>(We0, att0, be0, We1, att1, be1, watt);
    fill_kernel<<<cdiv(E, 256), 256, 0, stream>>>(ei, ea, E, watt, cursor, packed);

    // ---- layer 0: 64 -> 64 ----
    nodelin_kernel<64, 64, false><<<cdiv(N, 64), 256, 0, stream>>>(
        emb, nullptr, x, Wm0, bm0, Ws0, bs0, att0, hWm8, hWsb, nscore, N);
    agg_kernel<64, 0><<<cdiv(N, 16), 256, 0, stream>>>(csroff, packed, nscore,
                                                       We0, be0, hWm8, hWsb, hbuf, N);

    // ---- layer 1: 64 -> 128 ----
    nodelin_kernel<128, 32, true><<<cdiv(N, 32), 256, 0, stream>>>(
        nullptr, hbuf, nullptr, Wm1, bm1, Ws1, bs1, att1, hWm8, hWsb, nscore, N);
    agg_kernel<128, 1><<<cdiv(N, 8), 256, 0, stream>>>(csroff, packed, nscore,
                                                       We1, be1, hWm8, hWsb, hbuf, N);

    // ---- global mean pool + classifier ----
    pool_sum_kernel<<<512, 128, 0, stream>>>(hbuf, batchh, gsum, N);
    classifier_kernel<<<G, 128, 0, stream>>>(gsum, batchh, N, Wc1, bc1, Wc2, bc2, (float*)d_out);
}